// Round 1
// baseline (204.670 us; speedup 1.0000x reference)
//
#include <hip/hip_runtime.h>
#include <hip/hip_bf16.h>

typedef unsigned short u16;
typedef __attribute__((ext_vector_type(8))) short bf16x8;
typedef __attribute__((ext_vector_type(4))) float f32x4;

__device__ __forceinline__ u16 f2bf(float x){
  union { float f; unsigned u; } v; v.f = x;
  unsigned r = v.u + 0x7fffu + ((v.u >> 16) & 1u);
  return (u16)(r >> 16);
}
__device__ __forceinline__ float fast_tanh(float x){
  x = fminf(fmaxf(x, -12.f), 12.f);
  float e = __expf(2.f * x);
  return (e - 1.f) / (e + 1.f);
}
__device__ __forceinline__ float fast_sig(float x){
  return 1.f / (1.f + __expf(-x));
}

// ---------------- prep: bf16 conversions + concat buffers ----------------
// regions (flat): W_feat 262144 | W_hid 262144 | W_ih 2097152 | W_hh 1048576
//                | onehot 131072 | prev_h 131072 | bias 2048   total 3934208
__global__ void prep_kernel(
    const float* __restrict__ Wfeat, const float* __restrict__ Whid,
    const float* __restrict__ Wih,   const float* __restrict__ Whh,
    const float* __restrict__ onehot,const float* __restrict__ prevh,
    const float* __restrict__ bih,   const float* __restrict__ bhh,
    u16* __restrict__ wfeat_b, u16* __restrict__ whid_b,
    u16* __restrict__ wcat, u16* __restrict__ xh, float* __restrict__ biascat)
{
  int idx = blockIdx.x * 256 + threadIdx.x;
  if (idx < 262144) { wfeat_b[idx] = f2bf(Wfeat[idx]); return; }
  idx -= 262144;
  if (idx < 262144) { whid_b[idx] = f2bf(Whid[idx]); return; }
  idx -= 262144;
  if (idx < 2097152) { int r = idx >> 10, k = idx & 1023; wcat[r*1536 + k] = f2bf(Wih[idx]); return; }
  idx -= 2097152;
  if (idx < 1048576) { int r = idx >> 9, k = idx & 511; wcat[r*1536 + 1024 + k] = f2bf(Whh[idx]); return; }
  idx -= 1048576;
  if (idx < 131072) { int b = idx >> 9, e = idx & 511; xh[b*1536 + 512 + e] = f2bf(onehot[idx]); return; }
  idx -= 131072;
  if (idx < 131072) { int b = idx >> 9, h = idx & 511; xh[b*1536 + 1024 + h] = f2bf(prevh[idx]); return; }
  idx -= 131072;
  if (idx < 2048) { biascat[idx] = bih[idx] + bhh[idx]; }
}

// ---------------- generic C = A(bf16,[M][lda]) @ W(bf16,[N][K])^T + bias ----------------
// tile 128x128, 4 waves, 16x16x32 MFMA; used for hidden_proj and gates.
__global__ __launch_bounds__(256) void gemm_bt_bias(
    const u16* __restrict__ Ab, int lda,
    const u16* __restrict__ Wb, int K,
    const float* __restrict__ bias,
    float* __restrict__ C, int ldc)
{
  __shared__ u16 sA[128][40];
  __shared__ u16 sW[128][40];
  const int tid = threadIdx.x;
  const int lane = tid & 63, wave = tid >> 6;
  const int wr = wave >> 1, wc = wave & 1;
  const int lr = lane & 15, kg = lane >> 4;
  const int m0 = blockIdx.x * 128, n0 = blockIdx.y * 128;
  const int sr = tid >> 1, sh = tid & 1;

  const f32x4 zero = {0.f, 0.f, 0.f, 0.f};
  f32x4 acc[4][4];
  #pragma unroll
  for (int i = 0; i < 4; ++i)
    #pragma unroll
    for (int j = 0; j < 4; ++j)
      acc[i][j] = zero;

  for (int kt = 0; kt < K; kt += 32) {
    __syncthreads();
    {
      const u16* ap = Ab + (size_t)(m0 + sr) * lda + kt + sh * 16;
      *(bf16x8*)&sA[sr][sh*16]     = *(const bf16x8*)ap;
      *(bf16x8*)&sA[sr][sh*16 + 8] = *(const bf16x8*)(ap + 8);
      const u16* wp = Wb + (size_t)(n0 + sr) * K + kt + sh * 16;
      *(bf16x8*)&sW[sr][sh*16]     = *(const bf16x8*)wp;
      *(bf16x8*)&sW[sr][sh*16 + 8] = *(const bf16x8*)(wp + 8);
    }
    __syncthreads();
    bf16x8 af[4], wf[4];
    #pragma unroll
    for (int mi = 0; mi < 4; ++mi) af[mi] = *(const bf16x8*)&sA[wr*64 + mi*16 + lr][kg*8];
    #pragma unroll
    for (int ni = 0; ni < 4; ++ni) wf[ni] = *(const bf16x8*)&sW[wc*64 + ni*16 + lr][kg*8];
    #pragma unroll
    for (int mi = 0; mi < 4; ++mi)
      #pragma unroll
      for (int ni = 0; ni < 4; ++ni)
        acc[mi][ni] = __builtin_amdgcn_mfma_f32_16x16x32_bf16(af[mi], wf[ni], acc[mi][ni], 0, 0, 0);
  }

  #pragma unroll
  for (int ni = 0; ni < 4; ++ni) {
    const int col = n0 + wc*64 + ni*16 + lr;
    const float bv = bias[col];
    #pragma unroll
    for (int mi = 0; mi < 4; ++mi) {
      const int row = m0 + wr*64 + mi*16 + kg*4;
      #pragma unroll
      for (int rr = 0; rr < 4; ++rr)
        C[(size_t)(row + rr) * ldc + col] = acc[mi][ni][rr] + bv;
    }
  }
}

// ---------------- energies: big GEMM fused with tanh + w_score reduction ----------------
// A = batch_H f32 [65536][512] (converted to bf16 while staging), W = W_feat bf16 [512][512].
// BM=64, BN=512 (full N -> batch_H read from HBM exactly once), 8 waves, each 64x64.
// epart[wave][m] = sum over this wave's 64 h-cols of tanh(fp + hp) * w_score.
__global__ __launch_bounds__(512) void energies_gemm(
    const float* __restrict__ A, const u16* __restrict__ Wb,
    const float* __restrict__ hp, const float* __restrict__ wsc,
    float* __restrict__ epart)
{
  __shared__ u16 sA[64][40];
  __shared__ u16 sW[512][40];
  const int tid = threadIdx.x;
  const int lane = tid & 63, wv = tid >> 6;       // wv = 0..7 -> col block
  const int lr = lane & 15, kg = lane >> 4;
  const int m0 = blockIdx.x * 64;
  const int bb = m0 >> 8;                          // batch index (64-row block within one b)
  const int ar = tid >> 3, ac = tid & 7;           // A staging: row, float4-slot

  const f32x4 zero = {0.f, 0.f, 0.f, 0.f};
  f32x4 acc[4][4];
  #pragma unroll
  for (int i = 0; i < 4; ++i)
    #pragma unroll
    for (int j = 0; j < 4; ++j)
      acc[i][j] = zero;

  for (int kt = 0; kt < 512; kt += 32) {
    __syncthreads();
    {  // stage A tile 64x32, f32 -> bf16
      float4 v = *(const float4*)(A + (size_t)(m0 + ar) * 512 + kt + ac * 4);
      ushort4 u;
      u.x = f2bf(v.x); u.y = f2bf(v.y); u.z = f2bf(v.z); u.w = f2bf(v.w);
      *(ushort4*)&sA[ar][ac * 4] = u;
    }
    {  // stage W tile 512x32 (bf16, L2-resident)
      const u16* wp = Wb + (size_t)tid * 512 + kt;
      #pragma unroll
      for (int i = 0; i < 4; ++i)
        *(bf16x8*)&sW[tid][i * 8] = *(const bf16x8*)(wp + i * 8);
    }
    __syncthreads();
    bf16x8 af[4], wf[4];
    #pragma unroll
    for (int mi = 0; mi < 4; ++mi) af[mi] = *(const bf16x8*)&sA[mi*16 + lr][kg*8];
    #pragma unroll
    for (int ni = 0; ni < 4; ++ni) wf[ni] = *(const bf16x8*)&sW[wv*64 + ni*16 + lr][kg*8];
    #pragma unroll
    for (int mi = 0; mi < 4; ++mi)
      #pragma unroll
      for (int ni = 0; ni < 4; ++ni)
        acc[mi][ni] = __builtin_amdgcn_mfma_f32_16x16x32_bf16(af[mi], wf[ni], acc[mi][ni], 0, 0, 0);
  }

  // epilogue: tanh(fp + hidden_proj) * w_score, reduce over this wave's 64 cols
  float hpv[4], wsv[4];
  #pragma unroll
  for (int ni = 0; ni < 4; ++ni) {
    const int col = wv*64 + ni*16 + lr;
    hpv[ni] = hp[bb*512 + col];
    wsv[ni] = wsc[col];
  }
  #pragma unroll
  for (int mi = 0; mi < 4; ++mi) {
    #pragma unroll
    for (int rr = 0; rr < 4; ++rr) {
      float s = 0.f;
      #pragma unroll
      for (int ni = 0; ni < 4; ++ni)
        s += fast_tanh(acc[mi][ni][rr] + hpv[ni]) * wsv[ni];
      // reduce over the 16 lanes (lane&15) holding the 16 cols of each fragment row
      s += __shfl_xor(s, 1, 64);
      s += __shfl_xor(s, 2, 64);
      s += __shfl_xor(s, 4, 64);
      s += __shfl_xor(s, 8, 64);
      if (lr == 0)
        epart[wv * 65536 + m0 + mi*16 + kg*4 + rr] = s;
    }
  }
}

// ---------------- softmax over S=256 per batch row ----------------
__global__ __launch_bounds__(256) void softmax_k(
    const float* __restrict__ epart, float* __restrict__ alpha)
{
  const int b = blockIdx.x, s = threadIdx.x;
  float e = 0.f;
  #pragma unroll
  for (int p = 0; p < 8; ++p) e += epart[p * 65536 + b * 256 + s];
  float mx = e;
  #pragma unroll
  for (int o = 32; o >= 1; o >>= 1) mx = fmaxf(mx, __shfl_xor(mx, o, 64));
  __shared__ float sm[4], ss[4];
  if ((s & 63) == 0) sm[s >> 6] = mx;
  __syncthreads();
  mx = fmaxf(fmaxf(sm[0], sm[1]), fmaxf(sm[2], sm[3]));
  float ex = __expf(e - mx);
  float sum = ex;
  #pragma unroll
  for (int o = 32; o >= 1; o >>= 1) sum += __shfl_xor(sum, o, 64);
  if ((s & 63) == 0) ss[s >> 6] = sum;
  __syncthreads();
  sum = ss[0] + ss[1] + ss[2] + ss[3];
  alpha[b * 256 + s] = ex / sum;
}

// ---------------- context[b,d] = sum_s alpha[b,s] * H[b,s,d]  -> xh[:,0:512] (bf16) ----------------
__global__ __launch_bounds__(256) void context_k(
    const float* __restrict__ H, const float* __restrict__ alpha, u16* __restrict__ xh)
{
  const int b = blockIdx.x, t = threadIdx.x;
  __shared__ float sal[256];
  sal[t] = alpha[b * 256 + t];
  __syncthreads();
  const float2* p = (const float2*)(H + (size_t)b * 131072) + t;
  float a0 = 0.f, a1 = 0.f;
  #pragma unroll 8
  for (int s = 0; s < 256; ++s) {
    float2 v = p[(size_t)s * 256];
    float al = sal[s];
    a0 += al * v.x;
    a1 += al * v.y;
  }
  xh[b * 1536 + 2*t]     = f2bf(a0);
  xh[b * 1536 + 2*t + 1] = f2bf(a1);
}

// ---------------- LSTM elementwise ----------------
__global__ __launch_bounds__(256) void lstm_k(
    const float* __restrict__ gates, const float* __restrict__ prev_c, float* __restrict__ out)
{
  const int idx = blockIdx.x * 256 + threadIdx.x;   // 0..131071
  const int b = idx >> 9, h = idx & 511;
  const float* g = gates + (size_t)b * 2048;
  const float gi = g[h], gf = g[512 + h], gg = g[1024 + h], go = g[1536 + h];
  const float c = fast_sig(gf) * prev_c[idx] + fast_sig(gi) * fast_tanh(gg);
  const float hn = fast_sig(go) * fast_tanh(c);
  out[idx] = hn;                // h_new
  out[131072 + idx] = c;        // c_new
}

extern "C" void kernel_launch(void* const* d_in, const int* in_sizes, int n_in,
                              void* d_out, int out_size, void* d_ws, size_t ws_size,
                              hipStream_t stream) {
  const float* prev_h  = (const float*)d_in[0];
  const float* prev_c  = (const float*)d_in[1];
  const float* batch_H = (const float*)d_in[2];
  const float* onehot  = (const float*)d_in[3];
  const float* W_feat  = (const float*)d_in[4];
  const float* W_hid   = (const float*)d_in[5];
  const float* b_hid   = (const float*)d_in[6];
  const float* w_score = (const float*)d_in[7];
  const float* W_ih    = (const float*)d_in[8];
  const float* W_hh    = (const float*)d_in[9];
  const float* b_ih    = (const float*)d_in[10];
  const float* b_hh    = (const float*)d_in[11];
  float* out = (float*)d_out;   // [h_new 131072 | c_new 131072 | alpha 65536]

  char* ws = (char*)d_ws;
  u16*   wfeat_b = (u16*)(ws);              //   524288 B
  u16*   whid_b  = (u16*)(ws + 524288);     //   524288 B
  u16*   wcat    = (u16*)(ws + 1048576);    //  6291456 B  [2048][1536] = [W_ih | W_hh]
  u16*   xh      = (u16*)(ws + 7340032);    //   786432 B  [256][1536] = [context|onehot|prev_h]
  float* biascat = (float*)(ws + 8126464);  //     8192 B
  float* hp      = (float*)(ws + 8134656);  //   524288 B  hidden_proj [256][512]
  float* epart   = (float*)(ws + 8658944);  //  2097152 B  [8][65536]
  float* gates   = (float*)(ws + 10756096); //  2097152 B  [256][2048]
  // total 12853248 bytes

  float* alpha = out + 262144;

  prep_kernel<<<15368, 256, 0, stream>>>(W_feat, W_hid, W_ih, W_hh, onehot, prev_h,
                                         b_ih, b_hh, wfeat_b, whid_b, wcat, xh, biascat);
  // hidden_proj = prev_h @ W_hid^T + b_hid   (A = xh prev_h slice, lda=1536)
  gemm_bt_bias<<<dim3(2, 4), 256, 0, stream>>>(xh + 1024, 1536, whid_b, 512, b_hid, hp, 512);
  // energies (fused feat_proj GEMM + tanh + w_score reduce)
  energies_gemm<<<1024, 512, 0, stream>>>(batch_H, wfeat_b, hp, w_score, epart);
  softmax_k<<<256, 256, 0, stream>>>(epart, alpha);
  context_k<<<256, 256, 0, stream>>>(batch_H, alpha, xh);
  // gates = [context|onehot|prev_h] @ [W_ih|W_hh]^T + (b_ih+b_hh)
  gemm_bt_bias<<<dim3(2, 16), 256, 0, stream>>>(xh, 1536, wcat, 1536, biascat, gates, 2048);
  lstm_k<<<512, 256, 0, stream>>>(gates, prev_c, out);
}

// Round 2
// 184.900 us; speedup vs baseline: 1.1069x; 1.1069x over previous
//
#include <hip/hip_runtime.h>
#include <hip/hip_bf16.h>

typedef unsigned short u16;
typedef __attribute__((ext_vector_type(8))) short bf16x8;
typedef __attribute__((ext_vector_type(4))) float f32x4;

typedef __attribute__((address_space(1))) const void gvoid;
typedef __attribute__((address_space(3))) void svoid;

__device__ __forceinline__ void gload16(const void* g, void* l) {
  __builtin_amdgcn_global_load_lds((gvoid*)g, (svoid*)l, 16, 0, 0);
}

__device__ __forceinline__ u16 f2bf(float x){
  union { float f; unsigned u; } v; v.f = x;
  unsigned r = v.u + 0x7fffu + ((v.u >> 16) & 1u);
  return (u16)(r >> 16);
}
__device__ __forceinline__ float bf2f(u16 x){
  union { float f; unsigned u; } v; v.u = ((unsigned)x) << 16;
  return v.f;
}
__device__ __forceinline__ float fast_tanh(float x){
  x = fminf(fmaxf(x, -12.f), 12.f);
  float e = __expf(2.f * x);
  return (e - 1.f) / (e + 1.f);
}
__device__ __forceinline__ float fast_sig(float x){
  return 1.f / (1.f + __expf(-x));
}

// ---------------- prep: bf16 conversions + concat buffers ----------------
__global__ void prep_kernel(
    const float* __restrict__ Wfeat, const float* __restrict__ Whid,
    const float* __restrict__ Wih,   const float* __restrict__ Whh,
    const float* __restrict__ onehot,const float* __restrict__ prevh,
    const float* __restrict__ bih,   const float* __restrict__ bhh,
    u16* __restrict__ wfeat_b, u16* __restrict__ whid_b,
    u16* __restrict__ wcat, u16* __restrict__ xh, float* __restrict__ biascat)
{
  int idx = blockIdx.x * 256 + threadIdx.x;
  if (idx < 262144) { wfeat_b[idx] = f2bf(Wfeat[idx]); return; }
  idx -= 262144;
  if (idx < 262144) { whid_b[idx] = f2bf(Whid[idx]); return; }
  idx -= 262144;
  if (idx < 2097152) { int r = idx >> 10, k = idx & 1023; wcat[r*1536 + k] = f2bf(Wih[idx]); return; }
  idx -= 2097152;
  if (idx < 1048576) { int r = idx >> 9, k = idx & 511; wcat[r*1536 + 1024 + k] = f2bf(Whh[idx]); return; }
  idx -= 1048576;
  if (idx < 131072) { int b = idx >> 9, e = idx & 511; xh[b*1536 + 512 + e] = f2bf(onehot[idx]); return; }
  idx -= 131072;
  if (idx < 131072) { int b = idx >> 9, h = idx & 511; xh[b*1536 + 1024 + h] = f2bf(prevh[idx]); return; }
  idx -= 131072;
  if (idx < 2048) { biascat[idx] = bih[idx] + bhh[idx]; }
}

// ---------------- batch_H f32 -> bf16 (pure BW) ----------------
__global__ __launch_bounds__(256) void convH_k(
    const float* __restrict__ in, u16* __restrict__ out)
{
  size_t i = ((size_t)blockIdx.x * 256 + threadIdx.x) * 8;
  float4 a = *(const float4*)(in + i);
  float4 b = *(const float4*)(in + i + 4);
  bf16x8 v;
  v[0] = (short)f2bf(a.x); v[1] = (short)f2bf(a.y);
  v[2] = (short)f2bf(a.z); v[3] = (short)f2bf(a.w);
  v[4] = (short)f2bf(b.x); v[5] = (short)f2bf(b.y);
  v[6] = (short)f2bf(b.z); v[7] = (short)f2bf(b.w);
  *(bf16x8*)(out + i) = v;
}

// ---------------- generic C = A(bf16,[M][lda]) @ W(bf16,[N][K])^T + bias ----------------
// tile 128x128, 4 waves, 16x16x32 MFMA; used for hidden_proj and gates.
__global__ __launch_bounds__(256) void gemm_bt_bias(
    const u16* __restrict__ Ab, int lda,
    const u16* __restrict__ Wb, int K,
    const float* __restrict__ bias,
    float* __restrict__ C, int ldc)
{
  __shared__ u16 sA[128][40];
  __shared__ u16 sW[128][40];
  const int tid = threadIdx.x;
  const int lane = tid & 63, wave = tid >> 6;
  const int wr = wave >> 1, wc = wave & 1;
  const int lr = lane & 15, kg = lane >> 4;
  const int m0 = blockIdx.x * 128, n0 = blockIdx.y * 128;
  const int sr = tid >> 1, sh = tid & 1;

  const f32x4 zero = {0.f, 0.f, 0.f, 0.f};
  f32x4 acc[4][4];
  #pragma unroll
  for (int i = 0; i < 4; ++i)
    #pragma unroll
    for (int j = 0; j < 4; ++j)
      acc[i][j] = zero;

  for (int kt = 0; kt < K; kt += 32) {
    __syncthreads();
    {
      const u16* ap = Ab + (size_t)(m0 + sr) * lda + kt + sh * 16;
      *(bf16x8*)&sA[sr][sh*16]     = *(const bf16x8*)ap;
      *(bf16x8*)&sA[sr][sh*16 + 8] = *(const bf16x8*)(ap + 8);
      const u16* wp = Wb + (size_t)(n0 + sr) * K + kt + sh * 16;
      *(bf16x8*)&sW[sr][sh*16]     = *(const bf16x8*)wp;
      *(bf16x8*)&sW[sr][sh*16 + 8] = *(const bf16x8*)(wp + 8);
    }
    __syncthreads();
    bf16x8 af[4], wf[4];
    #pragma unroll
    for (int mi = 0; mi < 4; ++mi) af[mi] = *(const bf16x8*)&sA[wr*64 + mi*16 + lr][kg*8];
    #pragma unroll
    for (int ni = 0; ni < 4; ++ni) wf[ni] = *(const bf16x8*)&sW[wc*64 + ni*16 + lr][kg*8];
    #pragma unroll
    for (int mi = 0; mi < 4; ++mi)
      #pragma unroll
      for (int ni = 0; ni < 4; ++ni)
        acc[mi][ni] = __builtin_amdgcn_mfma_f32_16x16x32_bf16(af[mi], wf[ni], acc[mi][ni], 0, 0, 0);
  }

  #pragma unroll
  for (int ni = 0; ni < 4; ++ni) {
    const int col = n0 + wc*64 + ni*16 + lr;
    const float bv = bias[col];
    #pragma unroll
    for (int mi = 0; mi < 4; ++mi) {
      const int row = m0 + wr*64 + mi*16 + kg*4;
      #pragma unroll
      for (int rr = 0; rr < 4; ++rr)
        C[(size_t)(row + rr) * ldc + col] = acc[mi][ni][rr] + bv;
    }
  }
}

// ---------------- energies: m97-structure GEMM fused with tanh + w_score reduce ----------
// A = Hb bf16 [65536][512], W = wfeat_b bf16 [512][512].
// 128x128 tile, 4 waves (2x2), BK=32, linear LDS, global_load_lds width=16.
// epart[p][m] , p = blockIdx.y*2 + wc  (8 column-blocks of 64 over N=512).
__global__ __launch_bounds__(256) void energies_gemm(
    const u16* __restrict__ Hb, const u16* __restrict__ Wb,
    const float* __restrict__ hp, const float* __restrict__ wsc,
    float* __restrict__ epart)
{
  __shared__ u16 sA[128 * 32];
  __shared__ u16 sW[128 * 32];
  const int tid = threadIdx.x;
  const int lane = tid & 63, wave = tid >> 6;
  const int wr = wave >> 1, wc = wave & 1;
  const int lr = lane & 15, kg = lane >> 4;
  const int m0 = blockIdx.x * 128, n0 = blockIdx.y * 128;
  const int b = m0 >> 8;                       // batch element of this row-block

  // staging geometry: wave handles LDS chunks {2*wave, 2*wave+1} (1 KiB each = 16 rows)
  const int c0 = wave * 2;
  const int lrow = lane >> 2, lcol8 = (lane & 3) * 8;
  const u16* gA = Hb + (size_t)(m0 + c0 * 16 + lrow) * 512 + lcol8;
  const u16* gW = Wb + (size_t)(n0 + c0 * 16 + lrow) * 512 + lcol8;
  u16* lA = sA + c0 * 512;
  u16* lW = sW + c0 * 512;

  const f32x4 zero = {0.f, 0.f, 0.f, 0.f};
  f32x4 acc[4][4];
  #pragma unroll
  for (int i = 0; i < 4; ++i)
    #pragma unroll
    for (int j = 0; j < 4; ++j)
      acc[i][j] = zero;

  for (int kt = 0; kt < 512; kt += 32) {
    __syncthreads();
    gload16(gA + kt,            lA);
    gload16(gA + kt + 16 * 512, lA + 512);
    gload16(gW + kt,            lW);
    gload16(gW + kt + 16 * 512, lW + 512);
    __syncthreads();
    bf16x8 af[4], wf[4];
    #pragma unroll
    for (int mi = 0; mi < 4; ++mi) af[mi] = *(const bf16x8*)&sA[(wr*64 + mi*16 + lr) * 32 + kg*8];
    #pragma unroll
    for (int ni = 0; ni < 4; ++ni) wf[ni] = *(const bf16x8*)&sW[(wc*64 + ni*16 + lr) * 32 + kg*8];
    #pragma unroll
    for (int mi = 0; mi < 4; ++mi)
      #pragma unroll
      for (int ni = 0; ni < 4; ++ni)
        acc[mi][ni] = __builtin_amdgcn_mfma_f32_16x16x32_bf16(af[mi], wf[ni], acc[mi][ni], 0, 0, 0);
  }

  // epilogue: tanh(fp + hidden_proj) * w_score, reduce over this wave's 64 cols
  float hpv[4], wsv[4];
  #pragma unroll
  for (int ni = 0; ni < 4; ++ni) {
    const int col = n0 + wc*64 + ni*16 + lr;
    hpv[ni] = hp[b*512 + col];
    wsv[ni] = wsc[col];
  }
  const int p = blockIdx.y * 2 + wc;
  #pragma unroll
  for (int mi = 0; mi < 4; ++mi) {
    #pragma unroll
    for (int rr = 0; rr < 4; ++rr) {
      float s = 0.f;
      #pragma unroll
      for (int ni = 0; ni < 4; ++ni)
        s += fast_tanh(acc[mi][ni][rr] + hpv[ni]) * wsv[ni];
      s += __shfl_xor(s, 1, 64);
      s += __shfl_xor(s, 2, 64);
      s += __shfl_xor(s, 4, 64);
      s += __shfl_xor(s, 8, 64);
      if (lr == 0)
        epart[p * 65536 + m0 + wr*64 + mi*16 + kg*4 + rr] = s;
    }
  }
}

// ---------------- softmax over S=256 per batch row ----------------
__global__ __launch_bounds__(256) void softmax_k(
    const float* __restrict__ epart, float* __restrict__ alpha)
{
  const int b = blockIdx.x, s = threadIdx.x;
  float e = 0.f;
  #pragma unroll
  for (int p = 0; p < 8; ++p) e += epart[p * 65536 + b * 256 + s];
  float mx = e;
  #pragma unroll
  for (int o = 32; o >= 1; o >>= 1) mx = fmaxf(mx, __shfl_xor(mx, o, 64));
  __shared__ float sm[4], ss[4];
  if ((s & 63) == 0) sm[s >> 6] = mx;
  __syncthreads();
  mx = fmaxf(fmaxf(sm[0], sm[1]), fmaxf(sm[2], sm[3]));
  float ex = __expf(e - mx);
  float sum = ex;
  #pragma unroll
  for (int o = 32; o >= 1; o >>= 1) sum += __shfl_xor(sum, o, 64);
  if ((s & 63) == 0) ss[s >> 6] = sum;
  __syncthreads();
  sum = ss[0] + ss[1] + ss[2] + ss[3];
  alpha[b * 256 + s] = ex / sum;
}

// ---------------- context[b,d] = sum_s alpha[b,s] * Hb[b,s,d]  -> xh[:,0:512] (bf16) -------
__global__ __launch_bounds__(256) void context_k(
    const u16* __restrict__ Hb, const float* __restrict__ alpha, u16* __restrict__ xh)
{
  const int bb = blockIdx.x, t = threadIdx.x;
  const int q = t >> 6, c = t & 63;       // s-quarter, col-group of 8
  __shared__ float sal[256];
  sal[t] = alpha[bb * 256 + t];
  __syncthreads();
  float a[8];
  #pragma unroll
  for (int j = 0; j < 8; ++j) a[j] = 0.f;
  const u16* p = Hb + (size_t)bb * 131072 + c * 8;
  for (int s = q * 64; s < q * 64 + 64; ++s) {
    bf16x8 v = *(const bf16x8*)(p + (size_t)s * 512);
    float al = sal[s];
    #pragma unroll
    for (int j = 0; j < 8; ++j)
      a[j] = fmaf(al, bf2f((u16)v[j]), a[j]);
  }
  __shared__ float red[256][8];
  #pragma unroll
  for (int j = 0; j < 8; ++j) red[t][j] = a[j];
  __syncthreads();
  if (q == 0) {
    #pragma unroll
    for (int j = 0; j < 8; ++j) {
      float s = red[t][j] + red[t + 64][j] + red[t + 128][j] + red[t + 192][j];
      xh[bb * 1536 + c * 8 + j] = f2bf(s);
    }
  }
}

// ---------------- LSTM elementwise ----------------
__global__ __launch_bounds__(256) void lstm_k(
    const float* __restrict__ gates, const float* __restrict__ prev_c, float* __restrict__ out)
{
  const int idx = blockIdx.x * 256 + threadIdx.x;   // 0..131071
  const int b = idx >> 9, h = idx & 511;
  const float* g = gates + (size_t)b * 2048;
  const float gi = g[h], gf = g[512 + h], gg = g[1024 + h], go = g[1536 + h];
  const float c = fast_sig(gf) * prev_c[idx] + fast_sig(gi) * fast_tanh(gg);
  const float hn = fast_sig(go) * fast_tanh(c);
  out[idx] = hn;                // h_new
  out[131072 + idx] = c;        // c_new
}

extern "C" void kernel_launch(void* const* d_in, const int* in_sizes, int n_in,
                              void* d_out, int out_size, void* d_ws, size_t ws_size,
                              hipStream_t stream) {
  const float* prev_h  = (const float*)d_in[0];
  const float* prev_c  = (const float*)d_in[1];
  const float* batch_H = (const float*)d_in[2];
  const float* onehot  = (const float*)d_in[3];
  const float* W_feat  = (const float*)d_in[4];
  const float* W_hid   = (const float*)d_in[5];
  const float* b_hid   = (const float*)d_in[6];
  const float* w_score = (const float*)d_in[7];
  const float* W_ih    = (const float*)d_in[8];
  const float* W_hh    = (const float*)d_in[9];
  const float* b_ih    = (const float*)d_in[10];
  const float* b_hh    = (const float*)d_in[11];
  float* out = (float*)d_out;   // [h_new 131072 | c_new 131072 | alpha 65536]

  char* ws = (char*)d_ws;
  u16*   Hb      = (u16*)(ws);               // 67108864 B  batch_H bf16 [65536][512]
  u16*   wfeat_b = (u16*)(ws + 67108864);    //   524288 B
  u16*   whid_b  = (u16*)(ws + 67633152);    //   524288 B
  u16*   wcat    = (u16*)(ws + 68157440);    //  6291456 B  [2048][1536] = [W_ih | W_hh]
  u16*   xh      = (u16*)(ws + 74448896);    //   786432 B  [256][1536] = [context|onehot|prev_h]
  float* biascat = (float*)(ws + 75235328);  //     8192 B
  float* hp      = (float*)(ws + 75243520);  //   524288 B  hidden_proj [256][512]
  float* epart   = (float*)(ws + 75767808);  //  2097152 B  [8][65536]
  float* gates   = (float*)(ws + 77864960);  //  2097152 B  [256][2048]
  // total 79962112 bytes

  float* alpha = out + 262144;

  prep_kernel<<<15368, 256, 0, stream>>>(W_feat, W_hid, W_ih, W_hh, onehot, prev_h,
                                         b_ih, b_hh, wfeat_b, whid_b, wcat, xh, biascat);
  convH_k<<<16384, 256, 0, stream>>>(batch_H, Hb);
  // hidden_proj = prev_h @ W_hid^T + b_hid   (A = xh prev_h slice, lda=1536)
  gemm_bt_bias<<<dim3(2, 4), 256, 0, stream>>>(xh + 1024, 1536, whid_b, 512, b_hid, hp, 512);
  // energies (fused feat_proj GEMM + tanh + w_score reduce), m97 structure
  energies_gemm<<<dim3(512, 4), 256, 0, stream>>>(Hb, wfeat_b, hp, w_score, epart);
  softmax_k<<<256, 256, 0, stream>>>(epart, alpha);
  context_k<<<256, 256, 0, stream>>>(Hb, alpha, xh);
  // gates = [context|onehot|prev_h] @ [W_ih|W_hh]^T + (b_ih+b_hh)
  gemm_bt_bias<<<dim3(2, 16), 256, 0, stream>>>(xh, 1536, wcat, 1536, biascat, gates, 2048);
  lstm_k<<<512, 256, 0, stream>>>(gates, prev_c, out);
}

// Round 3
// 118.868 us; speedup vs baseline: 1.7218x; 1.5555x over previous
//
#include <hip/hip_runtime.h>
#include <hip/hip_bf16.h>

typedef unsigned short u16;
typedef __attribute__((ext_vector_type(8))) short bf16x8;
typedef __attribute__((ext_vector_type(4))) float f32x4;

typedef __attribute__((address_space(1))) const void gvoid;
typedef __attribute__((address_space(3))) void svoid;

__device__ __forceinline__ void gload16(const void* g, void* l) {
  __builtin_amdgcn_global_load_lds((gvoid*)g, (svoid*)l, 16, 0, 0);
}

__device__ __forceinline__ u16 f2bf(float x){
  union { float f; unsigned u; } v; v.f = x;
  unsigned r = v.u + 0x7fffu + ((v.u >> 16) & 1u);
  return (u16)(r >> 16);
}
__device__ __forceinline__ float fast_tanh(float x){
  x = fminf(fmaxf(x, -12.f), 12.f);
  float e = __expf(2.f * x);
  return (e - 1.f) / (e + 1.f);
}
__device__ __forceinline__ float fast_sig(float x){
  return 1.f / (1.f + __expf(-x));
}

// ---------------- prep: bf16 conversions + concat buffers (4 elems/thread) ----------------
__global__ __launch_bounds__(256) void prep_kernel(
    const float* __restrict__ Wfeat, const float* __restrict__ Whid,
    const float* __restrict__ Wih,   const float* __restrict__ Whh,
    const float* __restrict__ onehot,const float* __restrict__ prevh,
    const float* __restrict__ bih,   const float* __restrict__ bhh,
    u16* __restrict__ wfeat_b, u16* __restrict__ whid_b,
    u16* __restrict__ wcat, u16* __restrict__ xh, float* __restrict__ biascat)
{
  int idx = (blockIdx.x * 256 + threadIdx.x) * 4;
  const float* src;
  u16* dst;
  if (idx < 262144) { src = Wfeat + idx; dst = wfeat_b + idx; }
  else if ((idx -= 262144) < 262144) { src = Whid + idx; dst = whid_b + idx; }
  else if ((idx -= 262144) < 2097152) {
    int r = idx >> 10, k = idx & 1023; src = Wih + idx; dst = wcat + r*1536 + k;
  }
  else if ((idx -= 2097152) < 1048576) {
    int r = idx >> 9, k = idx & 511; src = Whh + idx; dst = wcat + r*1536 + 1024 + k;
  }
  else if ((idx -= 1048576) < 131072) {
    int b = idx >> 9, e = idx & 511; src = onehot + idx; dst = xh + b*1536 + 512 + e;
  }
  else if ((idx -= 131072) < 131072) {
    int b = idx >> 9, h = idx & 511; src = prevh + idx; dst = xh + b*1536 + 1024 + h;
  }
  else {
    idx -= 131072;
    if (idx < 2048) {
      float4 a = *(const float4*)(bih + idx);
      float4 b = *(const float4*)(bhh + idx);
      float4 c = { a.x + b.x, a.y + b.y, a.z + b.z, a.w + b.w };
      *(float4*)(biascat + idx) = c;
    }
    return;
  }
  float4 v = *(const float4*)src;
  ushort4 u;
  u.x = f2bf(v.x); u.y = f2bf(v.y); u.z = f2bf(v.z); u.w = f2bf(v.w);
  *(ushort4*)dst = u;
}

// ---------------- split-K partial GEMM: P[z] = A(bf16,[M][lda]) @ W(bf16,[N][ldw])^T ------
// tile 128x128, 4 waves, 16x16x32 MFMA. blockIdx.z = K-split index.
__global__ __launch_bounds__(256) void gemm_btk(
    const u16* __restrict__ Ab, int lda,
    const u16* __restrict__ Wb, int ldw,
    int ksteps, int pstride,
    float* __restrict__ P, int ldc)
{
  __shared__ u16 sA[128][40];
  __shared__ u16 sW[128][40];
  const int tid = threadIdx.x;
  const int lane = tid & 63, wave = tid >> 6;
  const int wr = wave >> 1, wc = wave & 1;
  const int lr = lane & 15, kg = lane >> 4;
  const int m0 = blockIdx.x * 128, n0 = blockIdx.y * 128;
  const int kbase = blockIdx.z * ksteps * 32;
  P += (size_t)blockIdx.z * pstride;
  const int sr = tid >> 1, sh = tid & 1;

  const f32x4 zero = {0.f, 0.f, 0.f, 0.f};
  f32x4 acc[4][4];
  #pragma unroll
  for (int i = 0; i < 4; ++i)
    #pragma unroll
    for (int j = 0; j < 4; ++j)
      acc[i][j] = zero;

  for (int ks = 0; ks < ksteps; ++ks) {
    const int kt = kbase + ks * 32;
    __syncthreads();
    {
      const u16* ap = Ab + (size_t)(m0 + sr) * lda + kt + sh * 16;
      *(bf16x8*)&sA[sr][sh*16]     = *(const bf16x8*)ap;
      *(bf16x8*)&sA[sr][sh*16 + 8] = *(const bf16x8*)(ap + 8);
      const u16* wp = Wb + (size_t)(n0 + sr) * ldw + kt + sh * 16;
      *(bf16x8*)&sW[sr][sh*16]     = *(const bf16x8*)wp;
      *(bf16x8*)&sW[sr][sh*16 + 8] = *(const bf16x8*)(wp + 8);
    }
    __syncthreads();
    bf16x8 af[4], wf[4];
    #pragma unroll
    for (int mi = 0; mi < 4; ++mi) af[mi] = *(const bf16x8*)&sA[wr*64 + mi*16 + lr][kg*8];
    #pragma unroll
    for (int ni = 0; ni < 4; ++ni) wf[ni] = *(const bf16x8*)&sW[wc*64 + ni*16 + lr][kg*8];
    #pragma unroll
    for (int mi = 0; mi < 4; ++mi)
      #pragma unroll
      for (int ni = 0; ni < 4; ++ni)
        acc[mi][ni] = __builtin_amdgcn_mfma_f32_16x16x32_bf16(af[mi], wf[ni], acc[mi][ni], 0, 0, 0);
  }

  #pragma unroll
  for (int ni = 0; ni < 4; ++ni) {
    const int col = n0 + wc*64 + ni*16 + lr;
    #pragma unroll
    for (int mi = 0; mi < 4; ++mi) {
      const int row = m0 + wr*64 + mi*16 + kg*4;
      #pragma unroll
      for (int rr = 0; rr < 4; ++rr)
        P[(size_t)(row + rr) * ldc + col] = acc[mi][ni][rr];
    }
  }
}

// ---------------- energies: f32 A staged+converted in-kernel, fused tanh/w_score ----------
// A = batch_H f32 [65536][512], W = wfeat_b bf16 [512][512].
// BM=128, BN=256, BK=32; 512 threads, 8 waves (2x4), per-wave 64x64.
// sA XOR-swizzled (reg-staged), sW linear (global_load_lds).
// hidden_proj = sum of 4 split-K partials + b_hid, folded into epilogue.
__global__ __launch_bounds__(512, 4) void energies_gemm(
    const float* __restrict__ A, const u16* __restrict__ Wb,
    const float* __restrict__ hpp, const float* __restrict__ bhid,
    const float* __restrict__ wsc, float* __restrict__ epart)
{
  __shared__ u16 sA[128 * 32];   //  8 KB
  __shared__ u16 sW[256 * 32];   // 16 KB
  const int tid = threadIdx.x;
  const int lane = tid & 63, wv = tid >> 6;
  const int wr = wv >> 2, wc = wv & 3;
  const int lr = lane & 15, kg = lane >> 4;
  const int m0 = blockIdx.x * 128, n0 = blockIdx.y * 256;
  const int b = m0 >> 8;

  // A staging: thread -> (row, 8-f32 chunk); swizzled LDS chunk = achk ^ ((arow>>1)&3)
  const int arow = tid >> 2, achk = tid & 3;
  const float* gA = A + (size_t)(m0 + arow) * 512 + achk * 8;
  u16* lA = sA + arow * 32 + (achk ^ ((arow >> 1) & 3)) * 8;

  // W staging: 2 x gload16/thread; wave wv chunk c covers rows wv*16 + c*128
  const u16* gW0 = Wb + (size_t)(n0 + wv * 16 + (lane >> 2)) * 512 + (lane & 3) * 8;
  const u16* gW1 = gW0 + 128 * 512;
  u16* lW0 = sW + wv * 512;
  u16* lW1 = lW0 + 4096;

  const f32x4 zero = {0.f, 0.f, 0.f, 0.f};
  f32x4 acc[4][4];
  #pragma unroll
  for (int i = 0; i < 4; ++i)
    #pragma unroll
    for (int j = 0; j < 4; ++j)
      acc[i][j] = zero;

  for (int kt = 0; kt < 512; kt += 32) {
    __syncthreads();
    float4 v0 = *(const float4*)(gA + kt);
    float4 v1 = *(const float4*)(gA + kt + 4);
    gload16(gW0 + kt, lW0);
    gload16(gW1 + kt, lW1);
    bf16x8 bv;
    bv[0] = (short)f2bf(v0.x); bv[1] = (short)f2bf(v0.y);
    bv[2] = (short)f2bf(v0.z); bv[3] = (short)f2bf(v0.w);
    bv[4] = (short)f2bf(v1.x); bv[5] = (short)f2bf(v1.y);
    bv[6] = (short)f2bf(v1.z); bv[7] = (short)f2bf(v1.w);
    *(bf16x8*)lA = bv;
    __syncthreads();
    bf16x8 af[4], wf[4];
    #pragma unroll
    for (int mi = 0; mi < 4; ++mi) {
      const int row = wr*64 + mi*16 + lr;
      af[mi] = *(const bf16x8*)&sA[row * 32 + (kg ^ ((row >> 1) & 3)) * 8];
    }
    #pragma unroll
    for (int ni = 0; ni < 4; ++ni)
      wf[ni] = *(const bf16x8*)&sW[(wc*64 + ni*16 + lr) * 32 + kg*8];
    #pragma unroll
    for (int mi = 0; mi < 4; ++mi)
      #pragma unroll
      for (int ni = 0; ni < 4; ++ni)
        acc[mi][ni] = __builtin_amdgcn_mfma_f32_16x16x32_bf16(af[mi], wf[ni], acc[mi][ni], 0, 0, 0);
  }

  // epilogue: hidden_proj reduce + bias, tanh, w_score, 16-lane reduce
  float hpv[4], wsv[4];
  #pragma unroll
  for (int ni = 0; ni < 4; ++ni) {
    const int col = n0 + wc*64 + ni*16 + lr;
    float h = bhid[col];
    #pragma unroll
    for (int z = 0; z < 4; ++z) h += hpp[z * 131072 + b * 512 + col];
    hpv[ni] = h;
    wsv[ni] = wsc[col];
  }
  const int p = blockIdx.y * 4 + wc;
  #pragma unroll
  for (int mi = 0; mi < 4; ++mi) {
    #pragma unroll
    for (int rr = 0; rr < 4; ++rr) {
      float s = 0.f;
      #pragma unroll
      for (int ni = 0; ni < 4; ++ni)
        s += fast_tanh(acc[mi][ni][rr] + hpv[ni]) * wsv[ni];
      s += __shfl_xor(s, 1, 64);
      s += __shfl_xor(s, 2, 64);
      s += __shfl_xor(s, 4, 64);
      s += __shfl_xor(s, 8, 64);
      if (lr == 0)
        epart[p * 65536 + m0 + wr*64 + mi*16 + kg*4 + rr] = s;
    }
  }
}

// ---------------- fused softmax + context (per batch element) ----------------
__global__ __launch_bounds__(256) void softctx_k(
    const float* __restrict__ epart, const float* __restrict__ H,
    float* __restrict__ alpha, u16* __restrict__ xh)
{
  const int bb = blockIdx.x, t = threadIdx.x;
  // softmax over S=256 (t = s index)
  float e = 0.f;
  #pragma unroll
  for (int p = 0; p < 8; ++p) e += epart[p * 65536 + bb * 256 + t];
  float mx = e;
  #pragma unroll
  for (int o = 32; o >= 1; o >>= 1) mx = fmaxf(mx, __shfl_xor(mx, o, 64));
  __shared__ float sm[4], ss[4];
  if ((t & 63) == 0) sm[t >> 6] = mx;
  __syncthreads();
  mx = fmaxf(fmaxf(sm[0], sm[1]), fmaxf(sm[2], sm[3]));
  float ex = __expf(e - mx);
  float sum = ex;
  #pragma unroll
  for (int o = 32; o >= 1; o >>= 1) sum += __shfl_xor(sum, o, 64);
  if ((t & 63) == 0) ss[t >> 6] = sum;
  __syncthreads();
  sum = ss[0] + ss[1] + ss[2] + ss[3];
  const float av = ex / sum;
  alpha[bb * 256 + t] = av;
  __shared__ float sal[256];
  sal[t] = av;
  __syncthreads();
  // context: q = s-quarter, c = col-group of 8 (f32 reads, L3-resident)
  const int q = t >> 6, c = t & 63;
  float a[8];
  #pragma unroll
  for (int j = 0; j < 8; ++j) a[j] = 0.f;
  const float* p = H + (size_t)bb * 131072 + c * 8;
  for (int s = q * 64; s < q * 64 + 64; ++s) {
    float4 v0 = *(const float4*)(p + (size_t)s * 512);
    float4 v1 = *(const float4*)(p + (size_t)s * 512 + 4);
    const float al = sal[s];
    a[0] = fmaf(al, v0.x, a[0]); a[1] = fmaf(al, v0.y, a[1]);
    a[2] = fmaf(al, v0.z, a[2]); a[3] = fmaf(al, v0.w, a[3]);
    a[4] = fmaf(al, v1.x, a[4]); a[5] = fmaf(al, v1.y, a[5]);
    a[6] = fmaf(al, v1.z, a[6]); a[7] = fmaf(al, v1.w, a[7]);
  }
  __shared__ float red[256][8];
  #pragma unroll
  for (int j = 0; j < 8; ++j) red[t][j] = a[j];
  __syncthreads();
  if (q == 0) {
    #pragma unroll
    for (int j = 0; j < 8; ++j) {
      float s = red[t][j] + red[t + 64][j] + red[t + 128][j] + red[t + 192][j];
      xh[bb * 1536 + c * 8 + j] = f2bf(s);
    }
  }
}

// ---------------- gates split-K reduce + bias + LSTM elementwise ----------------
__global__ __launch_bounds__(256) void lstm_reduce(
    const float* __restrict__ P, const float* __restrict__ biascat,
    const float* __restrict__ prev_c, float* __restrict__ out)
{
  const int idx = blockIdx.x * 256 + threadIdx.x;   // 0..131071
  const int b = idx >> 9, h = idx & 511;
  float gi = biascat[h], gf = biascat[512 + h], gg = biascat[1024 + h], go = biascat[1536 + h];
  #pragma unroll
  for (int z = 0; z < 4; ++z) {
    const float* q = P + (size_t)z * 524288 + (size_t)b * 2048;
    gi += q[h]; gf += q[512 + h]; gg += q[1024 + h]; go += q[1536 + h];
  }
  const float c = fast_sig(gf) * prev_c[idx] + fast_sig(gi) * fast_tanh(gg);
  out[idx] = fast_sig(go) * fast_tanh(c);   // h_new
  out[131072 + idx] = c;                     // c_new
}

extern "C" void kernel_launch(void* const* d_in, const int* in_sizes, int n_in,
                              void* d_out, int out_size, void* d_ws, size_t ws_size,
                              hipStream_t stream) {
  const float* prev_h  = (const float*)d_in[0];
  const float* prev_c  = (const float*)d_in[1];
  const float* batch_H = (const float*)d_in[2];
  const float* onehot  = (const float*)d_in[3];
  const float* W_feat  = (const float*)d_in[4];
  const float* W_hid   = (const float*)d_in[5];
  const float* b_hid   = (const float*)d_in[6];
  const float* w_score = (const float*)d_in[7];
  const float* W_ih    = (const float*)d_in[8];
  const float* W_hh    = (const float*)d_in[9];
  const float* b_ih    = (const float*)d_in[10];
  const float* b_hh    = (const float*)d_in[11];
  float* out = (float*)d_out;   // [h_new 131072 | c_new 131072 | alpha 65536]

  char* ws = (char*)d_ws;
  u16*   wfeat_b = (u16*)(ws);               //   524288 B
  u16*   whid_b  = (u16*)(ws + 524288);      //   524288 B
  u16*   wcat    = (u16*)(ws + 1048576);     //  6291456 B  [2048][1536] = [W_ih | W_hh]
  u16*   xh      = (u16*)(ws + 7340032);     //   786432 B  [256][1536] = [context|onehot|prev_h]
  float* biascat = (float*)(ws + 8126464);   //     8192 B
  float* hpp     = (float*)(ws + 8134656);   //  2097152 B  hidden partials [4][256][512]
  float* epart   = (float*)(ws + 10231808);  //  2097152 B  [8][65536]
  float* gpart   = (float*)(ws + 12328960);  //  8388608 B  gate partials [4][256][2048]
  // total 20717568 bytes

  float* alpha = out + 262144;

  prep_kernel<<<3842, 256, 0, stream>>>(W_feat, W_hid, W_ih, W_hh, onehot, prev_h,
                                        b_ih, b_hh, wfeat_b, whid_b, wcat, xh, biascat);
  // hidden_proj partials: prev_h @ W_hid^T  (split-K x4, bias folded into energies)
  gemm_btk<<<dim3(2, 4, 4), 256, 0, stream>>>(xh + 1024, 1536, whid_b, 512, 4, 131072, hpp, 512);
  // energies: fused feat_proj GEMM + hidden-reduce + tanh + w_score reduce
  energies_gemm<<<dim3(512, 2), 512, 0, stream>>>(batch_H, wfeat_b, hpp, b_hid, w_score, epart);
  // softmax + context (writes alpha output and xh context slice)
  softctx_k<<<256, 256, 0, stream>>>(epart, batch_H, alpha, xh);
  // gates partials: [context|onehot|prev_h] @ [W_ih|W_hh]^T (split-K x4)
  gemm_btk<<<dim3(2, 16, 4), 256, 0, stream>>>(xh, 1536, wcat, 1536, 12, 524288, gpart, 2048);
  // reduce + bias + LSTM
  lstm_reduce<<<512, 256, 0, stream>>>(gpart, biascat, prev_c, out);
}